// Round 1
// baseline (5694.719 us; speedup 1.0000x reference)
//
#include <hip/hip_runtime.h>

#define D 128
#define KC 16
#define TM 64  // rows per block in fused GEMM

// ---------------------------------------------------------------------------
// Scatter: msg[dst] += h[src] for each edge, 32 threads per edge (float4 each)
// ---------------------------------------------------------------------------
__global__ __launch_bounds__(256) void scatter_kernel(
    const float* __restrict__ h, const int* __restrict__ src,
    const int* __restrict__ dst, float* __restrict__ msg, int n_edges)
{
    int tid = blockIdx.x * 256 + threadIdx.x;
    int e = tid >> 5;
    if (e >= n_edges) return;
    int c = (tid & 31) * 4;
    int s = src[e];
    int d = dst[e];
    const float4 v = *(const float4*)(h + (size_t)s * D + c);
    float* p = msg + (size_t)d * D + c;
    atomicAdd(p + 0, v.x);
    atomicAdd(p + 1, v.y);
    atomicAdd(p + 2, v.z);
    atomicAdd(p + 3, v.w);
}

// ---------------------------------------------------------------------------
// Fused dual-GEMM: C = A @ Ws + (Msg * inv_deg) @ Wn + bias, optional LN+ReLU.
// Treated as single GEMM X[N][256] @ W[256][128] with X = [A | Msg*inv].
// Block: 256 threads, 64 rows x 128 cols; each thread 4 rows x 8 cols.
// ---------------------------------------------------------------------------
__global__ __launch_bounds__(256) void fused_layer_kernel(
    const float* __restrict__ A, const float* __restrict__ Msg,
    const int* __restrict__ in_deg,
    const float* __restrict__ Ws, const float* __restrict__ Wn,
    const float* __restrict__ bias,
    const float* __restrict__ ln_g, const float* __restrict__ ln_b,
    float* __restrict__ C, int N, int do_ln_relu)
{
    __shared__ float sX[TM][KC + 1];   // +1 pad: avoid bank conflicts on a-reads
    __shared__ float sW[KC][D];

    const int tid = threadIdx.x;
    const int tx = tid & 15;      // col group: cols tx*8 .. tx*8+7
    const int ty = tid >> 4;      // row group: rows ty*4 .. ty*4+3
    const int row0 = blockIdx.x * TM;
    const int c0 = tx * 8;

    float acc[4][8];
#pragma unroll
    for (int i = 0; i < 4; i++)
#pragma unroll
        for (int j = 0; j < 8; j++) acc[i][j] = 0.f;

    // sX loader mapping: thread t loads row lr, float4 at lf
    const int lr = tid >> 2;          // 0..63
    const int lf = (tid & 3) * 4;     // 0,4,8,12
    const int grow = row0 + lr;
    float invd = 1.f;
    if (grow < N) {
        int dg = in_deg[grow];
        invd = 1.f / (float)(dg > 1 ? dg : 1);
    }

    for (int k0 = 0; k0 < 2 * D; k0 += KC) {
        // --- load W chunk (16 x 128) ---
        const float* W = (k0 < D) ? (Ws + (size_t)k0 * D) : (Wn + (size_t)(k0 - D) * D);
#pragma unroll
        for (int rep = 0; rep < 2; rep++) {
            int ii = tid + rep * 256;          // float4 index 0..511
            int r = ii >> 5;
            int c = (ii & 31) * 4;
            float4 w = *(const float4*)(W + r * D + c);
            sW[r][c + 0] = w.x; sW[r][c + 1] = w.y;
            sW[r][c + 2] = w.z; sW[r][c + 3] = w.w;
        }
        // --- load X chunk (64 rows x 16 k) ---
        {
            float4 v = make_float4(0.f, 0.f, 0.f, 0.f);
            if (grow < N) {
                if (k0 < D) {
                    v = *(const float4*)(A + (size_t)grow * D + k0 + lf);
                } else {
                    v = *(const float4*)(Msg + (size_t)grow * D + (k0 - D) + lf);
                    v.x *= invd; v.y *= invd; v.z *= invd; v.w *= invd;
                }
            }
            sX[lr][lf + 0] = v.x; sX[lr][lf + 1] = v.y;
            sX[lr][lf + 2] = v.z; sX[lr][lf + 3] = v.w;
        }
        __syncthreads();

#pragma unroll
        for (int k = 0; k < KC; k++) {
            float a0 = sX[ty * 4 + 0][k];
            float a1 = sX[ty * 4 + 1][k];
            float a2 = sX[ty * 4 + 2][k];
            float a3 = sX[ty * 4 + 3][k];
            float w[8];
#pragma unroll
            for (int j = 0; j < 8; j++) w[j] = sW[k][c0 + j];
#pragma unroll
            for (int j = 0; j < 8; j++) {
                acc[0][j] += a0 * w[j];
                acc[1][j] += a1 * w[j];
                acc[2][j] += a2 * w[j];
                acc[3][j] += a3 * w[j];
            }
        }
        __syncthreads();
    }

    // --- epilogue ---
    float bb[8];
#pragma unroll
    for (int j = 0; j < 8; j++) bb[j] = bias[c0 + j];
    float gg[8], be[8];
    if (do_ln_relu) {
#pragma unroll
        for (int j = 0; j < 8; j++) { gg[j] = ln_g[c0 + j]; be[j] = ln_b[c0 + j]; }
    }

#pragma unroll
    for (int i = 0; i < 4; i++) {
        int row = row0 + ty * 4 + i;
        float v[8];
#pragma unroll
        for (int j = 0; j < 8; j++) v[j] = acc[i][j] + bb[j];

        if (do_ln_relu) {
            float s = 0.f, s2 = 0.f;
#pragma unroll
            for (int j = 0; j < 8; j++) { s += v[j]; s2 += v[j] * v[j]; }
            // row spans 16 consecutive lanes (same ty, tx=0..15) within a wave
#pragma unroll
            for (int off = 1; off < 16; off <<= 1) {
                s  += __shfl_xor(s,  off);
                s2 += __shfl_xor(s2, off);
            }
            float mean = s * (1.f / 128.f);
            float var  = s2 * (1.f / 128.f) - mean * mean;
            float rstd = rsqrtf(var + 1e-5f);
#pragma unroll
            for (int j = 0; j < 8; j++) {
                float t = (v[j] - mean) * rstd * gg[j] + be[j];
                v[j] = t > 0.f ? t : 0.f;
            }
        }

        if (row < N) {
            float4 o0 = make_float4(v[0], v[1], v[2], v[3]);
            float4 o1 = make_float4(v[4], v[5], v[6], v[7]);
            *(float4*)(C + (size_t)row * D + c0 + 0) = o0;
            *(float4*)(C + (size_t)row * D + c0 + 4) = o1;
        }
    }
}

// ---------------------------------------------------------------------------
extern "C" void kernel_launch(void* const* d_in, const int* in_sizes, int n_in,
                              void* d_out, int out_size, void* d_ws, size_t ws_size,
                              hipStream_t stream)
{
    const float* feat = (const float*)d_in[0];
    const float* Ws0  = (const float*)d_in[1];
    const float* Wn0  = (const float*)d_in[2];
    const float* b0   = (const float*)d_in[3];
    const float* Ws1  = (const float*)d_in[4];
    const float* Wn1  = (const float*)d_in[5];
    const float* b1   = (const float*)d_in[6];
    const float* lng  = (const float*)d_in[7];
    const float* lnb  = (const float*)d_in[8];
    const int* esrc   = (const int*)d_in[9];
    const int* edst   = (const int*)d_in[10];
    const int* indeg  = (const int*)d_in[11];

    const int N = 100000;
    const int E = in_sizes[9];

    float* out = (float*)d_out;           // doubles as msg buffer both layers
    float* msg = out;                     // N*D floats == out_size exactly
    float* h1  = (float*)d_ws;            // N*D floats of scratch

    const int scatter_blocks = (E * 32 + 255) / 256;
    const int gemm_blocks = (N + TM - 1) / TM;

    // Layer 0
    hipMemsetAsync(msg, 0, (size_t)N * D * sizeof(float), stream);
    scatter_kernel<<<scatter_blocks, 256, 0, stream>>>(feat, esrc, edst, msg, E);
    fused_layer_kernel<<<gemm_blocks, 256, 0, stream>>>(
        feat, msg, indeg, Ws0, Wn0, b0, lng, lnb, h1, N, 1);

    // Layer 1 (msg reuses d_out; fused kernel overwrites its own rows in place)
    hipMemsetAsync(msg, 0, (size_t)N * D * sizeof(float), stream);
    scatter_kernel<<<scatter_blocks, 256, 0, stream>>>(h1, esrc, edst, msg, E);
    fused_layer_kernel<<<gemm_blocks, 256, 0, stream>>>(
        h1, msg, indeg, Ws1, Wn1, b1, nullptr, nullptr, out, N, 0);
}

// Round 2
// 711.451 us; speedup vs baseline: 8.0044x; 8.0044x over previous
//
#include <hip/hip_runtime.h>

#define D 128
#define KC 16
#define TM 64
#define NN 100000

// ---------------------------------------------------------------------------
// CSR build: histogram -> exclusive scan (3 kernels) -> fill buckets
// ---------------------------------------------------------------------------
__global__ __launch_bounds__(256) void hist_kernel(
    const int* __restrict__ dst, int* __restrict__ counts, int E)
{
    int e = blockIdx.x * 256 + threadIdx.x;
    if (e < E) atomicAdd(&counts[dst[e]], 1);
}

// 1024 elements per block (256 threads x 4): local exclusive scan + block sums
__global__ __launch_bounds__(256) void scan1_kernel(
    const int* __restrict__ counts, int* __restrict__ row_ptr,
    int* __restrict__ blockSums, int N)
{
    __shared__ int sd[256];
    int t = threadIdx.x;
    int base = blockIdx.x * 1024;
    int v[4]; int tot = 0;
#pragma unroll
    for (int i = 0; i < 4; i++) {
        int idx = base + t * 4 + i;
        v[i] = (idx < N) ? counts[idx] : 0;
        tot += v[i];
    }
    sd[t] = tot; __syncthreads();
    for (int off = 1; off < 256; off <<= 1) {
        int x = (t >= off) ? sd[t - off] : 0;
        __syncthreads();
        sd[t] += x;
        __syncthreads();
    }
    int excl = sd[t] - tot;
    if (t == 255) blockSums[blockIdx.x] = sd[255];
    int run = excl;
#pragma unroll
    for (int i = 0; i < 4; i++) {
        int idx = base + t * 4 + i;
        if (idx < N) row_ptr[idx] = run;
        run += v[i];
    }
}

// single block: exclusive scan of nb (<=256) block sums
__global__ __launch_bounds__(256) void scan2_kernel(
    const int* __restrict__ blockSums, int* __restrict__ blockOffs, int nb)
{
    __shared__ int sd[256];
    int t = threadIdx.x;
    int val = (t < nb) ? blockSums[t] : 0;
    sd[t] = val; __syncthreads();
    for (int off = 1; off < 256; off <<= 1) {
        int x = (t >= off) ? sd[t - off] : 0;
        __syncthreads();
        sd[t] += x;
        __syncthreads();
    }
    if (t < nb) blockOffs[t] = sd[t] - val;
}

__global__ __launch_bounds__(256) void scan3_kernel(
    int* __restrict__ row_ptr, const int* __restrict__ blockOffs, int N, int E)
{
    int i = blockIdx.x * 256 + threadIdx.x;
    if (i < N) row_ptr[i] += blockOffs[i >> 10];
    if (i == N) row_ptr[N] = E;
}

__global__ __launch_bounds__(256) void fill_kernel(
    const int* __restrict__ src, const int* __restrict__ dst,
    const int* __restrict__ row_ptr, int* __restrict__ fillc,
    int* __restrict__ col, int E)
{
    int e = blockIdx.x * 256 + threadIdx.x;
    if (e >= E) return;
    int d = dst[e];
    int pos = atomicAdd(&fillc[d], 1);
    col[row_ptr[d] + pos] = src[e];
}

// ---------------------------------------------------------------------------
// Gather: msg[node] = sum over neighbors h[col[j]]. One wave per node,
// 64 lanes x float2 (coalesced 512B per neighbor row). No atomics.
// ---------------------------------------------------------------------------
__global__ __launch_bounds__(256) void gather_kernel(
    const float* __restrict__ h, const int* __restrict__ row_ptr,
    const int* __restrict__ col, float* __restrict__ msg, int N)
{
    int node = blockIdx.x * 4 + (threadIdx.x >> 6);
    int lane = threadIdx.x & 63;
    if (node >= N) return;
    int beg = row_ptr[node];
    int end = row_ptr[node + 1];
    float2 acc = make_float2(0.f, 0.f);
    int j = beg;
    for (; j + 4 <= end; j += 4) {
        int c0 = col[j], c1 = col[j + 1], c2 = col[j + 2], c3 = col[j + 3];
        float2 v0 = *(const float2*)(h + (size_t)c0 * D + lane * 2);
        float2 v1 = *(const float2*)(h + (size_t)c1 * D + lane * 2);
        float2 v2 = *(const float2*)(h + (size_t)c2 * D + lane * 2);
        float2 v3 = *(const float2*)(h + (size_t)c3 * D + lane * 2);
        acc.x += v0.x + v1.x + v2.x + v3.x;
        acc.y += v0.y + v1.y + v2.y + v3.y;
    }
    for (; j < end; ++j) {
        int c = col[j];
        float2 v = *(const float2*)(h + (size_t)c * D + lane * 2);
        acc.x += v.x; acc.y += v.y;
    }
    *(float2*)(msg + (size_t)node * D + lane * 2) = acc;
}

// ---------------------------------------------------------------------------
// Fallback scatter (only used if ws_size is too small for CSR)
// ---------------------------------------------------------------------------
__global__ __launch_bounds__(256) void scatter_kernel(
    const float* __restrict__ h, const int* __restrict__ src,
    const int* __restrict__ dst, float* __restrict__ msg, int n_edges)
{
    int tid = blockIdx.x * 256 + threadIdx.x;
    int e = tid >> 5;
    if (e >= n_edges) return;
    int c = (tid & 31) * 4;
    int s = src[e];
    int d = dst[e];
    const float4 v = *(const float4*)(h + (size_t)s * D + c);
    float* p = msg + (size_t)d * D + c;
    atomicAdd(p + 0, v.x);
    atomicAdd(p + 1, v.y);
    atomicAdd(p + 2, v.z);
    atomicAdd(p + 3, v.w);
}

// ---------------------------------------------------------------------------
// Fused dual-GEMM: C = A @ Ws + (Msg * inv_deg) @ Wn + bias, optional LN+ReLU.
// X[N][256] @ W[256][128] with X = [A | Msg*inv]. 64 rows x 128 cols / block.
// ---------------------------------------------------------------------------
__global__ __launch_bounds__(256) void fused_layer_kernel(
    const float* __restrict__ A, const float* __restrict__ Msg,
    const int* __restrict__ in_deg,
    const float* __restrict__ Ws, const float* __restrict__ Wn,
    const float* __restrict__ bias,
    const float* __restrict__ ln_g, const float* __restrict__ ln_b,
    float* __restrict__ C, int N, int do_ln_relu)
{
    __shared__ float sX[TM][KC + 1];
    __shared__ float sW[KC][D];

    const int tid = threadIdx.x;
    const int tx = tid & 15;
    const int ty = tid >> 4;
    const int row0 = blockIdx.x * TM;
    const int c0 = tx * 8;

    float acc[4][8];
#pragma unroll
    for (int i = 0; i < 4; i++)
#pragma unroll
        for (int j = 0; j < 8; j++) acc[i][j] = 0.f;

    const int lr = tid >> 2;
    const int lf = (tid & 3) * 4;
    const int grow = row0 + lr;
    float invd = 1.f;
    if (grow < N) {
        int dg = in_deg[grow];
        invd = 1.f / (float)(dg > 1 ? dg : 1);
    }

    for (int k0 = 0; k0 < 2 * D; k0 += KC) {
        const float* W = (k0 < D) ? (Ws + (size_t)k0 * D) : (Wn + (size_t)(k0 - D) * D);
#pragma unroll
        for (int rep = 0; rep < 2; rep++) {
            int ii = tid + rep * 256;
            int r = ii >> 5;
            int c = (ii & 31) * 4;
            float4 w = *(const float4*)(W + r * D + c);
            sW[r][c + 0] = w.x; sW[r][c + 1] = w.y;
            sW[r][c + 2] = w.z; sW[r][c + 3] = w.w;
        }
        {
            float4 v = make_float4(0.f, 0.f, 0.f, 0.f);
            if (grow < N) {
                if (k0 < D) {
                    v = *(const float4*)(A + (size_t)grow * D + k0 + lf);
                } else {
                    v = *(const float4*)(Msg + (size_t)grow * D + (k0 - D) + lf);
                    v.x *= invd; v.y *= invd; v.z *= invd; v.w *= invd;
                }
            }
            sX[lr][lf + 0] = v.x; sX[lr][lf + 1] = v.y;
            sX[lr][lf + 2] = v.z; sX[lr][lf + 3] = v.w;
        }
        __syncthreads();

#pragma unroll
        for (int k = 0; k < KC; k++) {
            float a0 = sX[ty * 4 + 0][k];
            float a1 = sX[ty * 4 + 1][k];
            float a2 = sX[ty * 4 + 2][k];
            float a3 = sX[ty * 4 + 3][k];
            float w[8];
#pragma unroll
            for (int j = 0; j < 8; j++) w[j] = sW[k][c0 + j];
#pragma unroll
            for (int j = 0; j < 8; j++) {
                acc[0][j] += a0 * w[j];
                acc[1][j] += a1 * w[j];
                acc[2][j] += a2 * w[j];
                acc[3][j] += a3 * w[j];
            }
        }
        __syncthreads();
    }

    float bb[8];
#pragma unroll
    for (int j = 0; j < 8; j++) bb[j] = bias[c0 + j];
    float gg[8], be[8];
    if (do_ln_relu) {
#pragma unroll
        for (int j = 0; j < 8; j++) { gg[j] = ln_g[c0 + j]; be[j] = ln_b[c0 + j]; }
    }

#pragma unroll
    for (int i = 0; i < 4; i++) {
        int row = row0 + ty * 4 + i;
        float v[8];
#pragma unroll
        for (int j = 0; j < 8; j++) v[j] = acc[i][j] + bb[j];

        if (do_ln_relu) {
            float s = 0.f, s2 = 0.f;
#pragma unroll
            for (int j = 0; j < 8; j++) { s += v[j]; s2 += v[j] * v[j]; }
#pragma unroll
            for (int off = 1; off < 16; off <<= 1) {
                s  += __shfl_xor(s,  off);
                s2 += __shfl_xor(s2, off);
            }
            float mean = s * (1.f / 128.f);
            float var  = s2 * (1.f / 128.f) - mean * mean;
            float rstd = rsqrtf(var + 1e-5f);
#pragma unroll
            for (int j = 0; j < 8; j++) {
                float t = (v[j] - mean) * rstd * gg[j] + be[j];
                v[j] = t > 0.f ? t : 0.f;
            }
        }

        if (row < N) {
            float4 o0 = make_float4(v[0], v[1], v[2], v[3]);
            float4 o1 = make_float4(v[4], v[5], v[6], v[7]);
            *(float4*)(C + (size_t)row * D + c0 + 0) = o0;
            *(float4*)(C + (size_t)row * D + c0 + 4) = o1;
        }
    }
}

// ---------------------------------------------------------------------------
extern "C" void kernel_launch(void* const* d_in, const int* in_sizes, int n_in,
                              void* d_out, int out_size, void* d_ws, size_t ws_size,
                              hipStream_t stream)
{
    const float* feat = (const float*)d_in[0];
    const float* Ws0  = (const float*)d_in[1];
    const float* Wn0  = (const float*)d_in[2];
    const float* b0   = (const float*)d_in[3];
    const float* Ws1  = (const float*)d_in[4];
    const float* Wn1  = (const float*)d_in[5];
    const float* b1   = (const float*)d_in[6];
    const float* lng  = (const float*)d_in[7];
    const float* lnb  = (const float*)d_in[8];
    const int* esrc   = (const int*)d_in[9];
    const int* edst   = (const int*)d_in[10];
    const int* indeg  = (const int*)d_in[11];

    const int N = NN;
    const int E = in_sizes[9];

    float* out = (float*)d_out;
    float* msg = out;                       // N*D floats == out_size

    // workspace layout (16B-aligned slabs)
    char* ws = (char*)d_ws;
    size_t o = 0;
    auto alloc = [&](size_t bytes) { char* p = ws + o; o += (bytes + 15) & ~(size_t)15; return p; };
    float* h1      = (float*)alloc((size_t)N * D * sizeof(float));
    int*   col     = (int*)  alloc((size_t)E * sizeof(int));
    int*   row_ptr = (int*)  alloc((size_t)(N + 1) * sizeof(int));
    int*   counts  = (int*)  alloc((size_t)N * sizeof(int));     // counts+fill adjacent
    int*   fillc   = (int*)  alloc((size_t)N * sizeof(int));
    int*   bsums   = (int*)  alloc(256 * sizeof(int));
    int*   boffs   = (int*)  alloc(256 * sizeof(int));
    bool have_ws = (o <= ws_size);

    const int gemm_blocks = (N + TM - 1) / TM;
    const int edge_blocks = (E + 255) / 256;

    if (have_ws) {
        // --- CSR build (once, shared by both layers) ---
        hipMemsetAsync(counts, 0, 2 * (size_t)N * sizeof(int), stream);  // counts + fillc
        hist_kernel<<<edge_blocks, 256, 0, stream>>>(edst, counts, E);
        int nb = (N + 1023) / 1024;
        scan1_kernel<<<nb, 256, 0, stream>>>(counts, row_ptr, bsums, N);
        scan2_kernel<<<1, 256, 0, stream>>>(bsums, boffs, nb);
        scan3_kernel<<<(N + 256) / 256, 256, 0, stream>>>(row_ptr, boffs, N, E);
        fill_kernel<<<edge_blocks, 256, 0, stream>>>(esrc, edst, row_ptr, fillc, col, E);

        // --- Layer 0 ---
        gather_kernel<<<(N + 3) / 4, 256, 0, stream>>>(feat, row_ptr, col, msg, N);
        fused_layer_kernel<<<gemm_blocks, 256, 0, stream>>>(
            feat, msg, indeg, Ws0, Wn0, b0, lng, lnb, h1, N, 1);

        // --- Layer 1 ---
        gather_kernel<<<(N + 3) / 4, 256, 0, stream>>>(h1, row_ptr, col, msg, N);
        fused_layer_kernel<<<gemm_blocks, 256, 0, stream>>>(
            h1, msg, indeg, Ws1, Wn1, b1, nullptr, nullptr, out, N, 0);
    } else {
        // fallback: atomic scatter path (needs only h1 in ws)
        float* h1f = (float*)d_ws;
        const int scatter_blocks = (E * 32 + 255) / 256;
        hipMemsetAsync(msg, 0, (size_t)N * D * sizeof(float), stream);
        scatter_kernel<<<scatter_blocks, 256, 0, stream>>>(feat, esrc, edst, msg, E);
        fused_layer_kernel<<<gemm_blocks, 256, 0, stream>>>(
            feat, msg, indeg, Ws0, Wn0, b0, lng, lnb, h1f, N, 1);
        hipMemsetAsync(msg, 0, (size_t)N * D * sizeof(float), stream);
        scatter_kernel<<<scatter_blocks, 256, 0, stream>>>(h1f, esrc, edst, msg, E);
        fused_layer_kernel<<<gemm_blocks, 256, 0, stream>>>(
            h1f, msg, indeg, Ws1, Wn1, b1, nullptr, nullptr, out, N, 0);
    }
}

// Round 3
// 454.012 us; speedup vs baseline: 12.5431x; 1.5670x over previous
//
#include <hip/hip_runtime.h>

#define D 128
#define NN 100000

typedef __attribute__((ext_vector_type(8))) short short8;
typedef __attribute__((ext_vector_type(4))) float floatx4;

__device__ inline unsigned short bf16_rne(float f) {
    unsigned int u = __float_as_uint(f);
    u += 0x7fff + ((u >> 16) & 1);
    return (unsigned short)(u >> 16);
}

// ---------------------------------------------------------------------------
// CSR build: hist (+rank) -> scan -> streaming fill (no atomics in fill)
// ---------------------------------------------------------------------------
__global__ __launch_bounds__(256) void hist_rank_kernel(
    const int* __restrict__ dst, int* __restrict__ counts,
    int* __restrict__ rank, int E)
{
    int e = blockIdx.x * 256 + threadIdx.x;
    if (e < E) rank[e] = atomicAdd(&counts[dst[e]], 1);
}

__global__ __launch_bounds__(256) void scan1_kernel(
    const int* __restrict__ counts, int* __restrict__ row_ptr,
    int* __restrict__ blockSums, int N)
{
    __shared__ int sd[256];
    int t = threadIdx.x;
    int base = blockIdx.x * 1024;
    int v[4]; int tot = 0;
#pragma unroll
    for (int i = 0; i < 4; i++) {
        int idx = base + t * 4 + i;
        v[i] = (idx < N) ? counts[idx] : 0;
        tot += v[i];
    }
    sd[t] = tot; __syncthreads();
    for (int off = 1; off < 256; off <<= 1) {
        int x = (t >= off) ? sd[t - off] : 0;
        __syncthreads();
        sd[t] += x;
        __syncthreads();
    }
    int excl = sd[t] - tot;
    if (t == 255) blockSums[blockIdx.x] = sd[255];
    int run = excl;
#pragma unroll
    for (int i = 0; i < 4; i++) {
        int idx = base + t * 4 + i;
        if (idx < N) row_ptr[idx] = run;
        run += v[i];
    }
}

__global__ __launch_bounds__(256) void scan2_kernel(
    const int* __restrict__ blockSums, int* __restrict__ blockOffs, int nb)
{
    __shared__ int sd[256];
    int t = threadIdx.x;
    int val = (t < nb) ? blockSums[t] : 0;
    sd[t] = val; __syncthreads();
    for (int off = 1; off < 256; off <<= 1) {
        int x = (t >= off) ? sd[t - off] : 0;
        __syncthreads();
        sd[t] += x;
        __syncthreads();
    }
    if (t < nb) blockOffs[t] = sd[t] - val;
}

__global__ __launch_bounds__(256) void scan3_kernel(
    int* __restrict__ row_ptr, const int* __restrict__ blockOffs, int N, int E)
{
    int i = blockIdx.x * 256 + threadIdx.x;
    if (i < N) row_ptr[i] += blockOffs[i >> 10];
    if (i == N) row_ptr[N] = E;
}

__global__ __launch_bounds__(256) void fill_stream_kernel(
    const int* __restrict__ src, const int* __restrict__ dst,
    const int* __restrict__ row_ptr, const int* __restrict__ rank,
    int* __restrict__ col, int E)
{
    int e = blockIdx.x * 256 + threadIdx.x;
    if (e >= E) return;
    col[row_ptr[dst[e]] + rank[e]] = src[e];
}

// ---------------------------------------------------------------------------
// fp32 -> bf16 conversions
// ---------------------------------------------------------------------------
__global__ __launch_bounds__(256) void cvt_bf16_kernel(
    const float* __restrict__ in, unsigned short* __restrict__ out, int n4)
{
    int i = blockIdx.x * 256 + threadIdx.x;
    if (i >= n4) return;
    float4 v = *(const float4*)(in + (size_t)i * 4);
    unsigned short u[4] = { bf16_rne(v.x), bf16_rne(v.y), bf16_rne(v.z), bf16_rne(v.w) };
    *(uint2*)(out + (size_t)i * 4) = *(uint2*)u;
}

// Wt[layer][n][k] bf16, n in [0,128), k in [0,256): k<128 -> Ws[k][n], else Wn[k-128][n]
__global__ __launch_bounds__(256) void build_wt_kernel(
    const float* __restrict__ Ws0, const float* __restrict__ Wn0,
    const float* __restrict__ Ws1, const float* __restrict__ Wn1,
    unsigned short* __restrict__ wt0, unsigned short* __restrict__ wt1)
{
    int i = blockIdx.x * 256 + threadIdx.x;   // 0 .. 65535
    int layer = i >> 15;
    int r = i & 32767;
    int n = r >> 8;
    int k = r & 255;
    const float* Ws = layer ? Ws1 : Ws0;
    const float* Wn = layer ? Wn1 : Wn0;
    float v = (k < 128) ? Ws[(size_t)k * 128 + n] : Wn[(size_t)(k - 128) * 128 + n];
    unsigned short* wt = layer ? wt1 : wt0;
    wt[(size_t)n * 256 + k] = bf16_rne(v);
}

// ---------------------------------------------------------------------------
// Gather (bf16 rows): msg[node] = inv_deg * sum_{j} h16[col[j]]   (fp32 out)
// One wave per node; lane reads 2 bf16 (4B) -> 256B/row coalesced.
// ---------------------------------------------------------------------------
__global__ __launch_bounds__(256) void gather_bf16_kernel(
    const unsigned short* __restrict__ h16, const int* __restrict__ row_ptr,
    const int* __restrict__ col, const int* __restrict__ in_deg,
    float* __restrict__ msg, int N)
{
    int node = blockIdx.x * 4 + (threadIdx.x >> 6);
    int lane = threadIdx.x & 63;
    if (node >= N) return;
    int beg = row_ptr[node];
    int end = row_ptr[node + 1];
    float ax = 0.f, ay = 0.f;
    int j = beg;
    for (; j + 4 <= end; j += 4) {
        int c0 = col[j], c1 = col[j + 1], c2 = col[j + 2], c3 = col[j + 3];
        unsigned int u0 = *(const unsigned int*)(h16 + (size_t)c0 * D + lane * 2);
        unsigned int u1 = *(const unsigned int*)(h16 + (size_t)c1 * D + lane * 2);
        unsigned int u2 = *(const unsigned int*)(h16 + (size_t)c2 * D + lane * 2);
        unsigned int u3 = *(const unsigned int*)(h16 + (size_t)c3 * D + lane * 2);
        ax += __uint_as_float(u0 << 16) + __uint_as_float(u1 << 16)
            + __uint_as_float(u2 << 16) + __uint_as_float(u3 << 16);
        ay += __uint_as_float(u0 & 0xffff0000u) + __uint_as_float(u1 & 0xffff0000u)
            + __uint_as_float(u2 & 0xffff0000u) + __uint_as_float(u3 & 0xffff0000u);
    }
    for (; j < end; ++j) {
        unsigned int u = *(const unsigned int*)(h16 + (size_t)col[j] * D + lane * 2);
        ax += __uint_as_float(u << 16);
        ay += __uint_as_float(u & 0xffff0000u);
    }
    int dg = in_deg[node];
    float invd = 1.f / (float)(dg > 1 ? dg : 1);
    *(float2*)(msg + (size_t)node * D + lane * 2) = make_float2(ax * invd, ay * invd);
}

// ---------------------------------------------------------------------------
// MFMA dual-GEMM: C[64 x 128] = X[64 x 256] @ Wcat[256 x 128] + bias (+LN+ReLU)
// X = [A16 | Msg(fp32, pre-scaled)]. 256 thr = 4 waves; wave w: rows w*16..+15.
// mfma_f32_16x16x32_bf16: A lane m=lane&15,k=quad*8+j; B lane n=lane&15,
// k=quad*8+j; C/D lane col=lane&15,row=quad*4+r.
// LDS rows padded to 40 ushorts (80B): 16B-aligned b128, conflict-free-ish.
// ---------------------------------------------------------------------------
__global__ __launch_bounds__(256) void mfma_layer_kernel(
    const unsigned short* __restrict__ A16, const float* __restrict__ Msg,
    const unsigned short* __restrict__ Wt,   // [128 n][256 k] bf16
    const float* __restrict__ bias,
    const float* __restrict__ ln_g, const float* __restrict__ ln_b,
    unsigned short* __restrict__ Out16, float* __restrict__ Out32,
    int N, int do_ln)
{
    __shared__ unsigned short sX[64 * 40];
    __shared__ unsigned short sW[128 * 40];

    const int tid = threadIdx.x;
    const int wave = tid >> 6;
    const int lane = tid & 63;
    const int quad = lane >> 4;
    const int ln16 = lane & 15;
    const int row0 = blockIdx.x * 64;

    floatx4 acc[8];
#pragma unroll
    for (int ct = 0; ct < 8; ct++) acc[ct] = (floatx4){0.f, 0.f, 0.f, 0.f};

    const int xr = tid >> 2;          // 0..63
    const int xo = (tid & 3) * 8;     // 0,8,16,24
    const int xrow_g = row0 + xr;
    const int wn = tid >> 1;          // 0..127
    const int wo = (tid & 1) * 16;    // 0,16

    for (int k0 = 0; k0 < 256; k0 += 32) {
        // --- stage X[64][32] ---
        uint4 xv = make_uint4(0u, 0u, 0u, 0u);
        if (xrow_g < N) {
            if (k0 < 128) {
                xv = *(const uint4*)(A16 + (size_t)xrow_g * D + k0 + xo);
            } else {
                const float* p = Msg + (size_t)xrow_g * D + (k0 - 128) + xo;
                float4 f0 = *(const float4*)(p);
                float4 f1 = *(const float4*)(p + 4);
                unsigned short us[8] = {
                    bf16_rne(f0.x), bf16_rne(f0.y), bf16_rne(f0.z), bf16_rne(f0.w),
                    bf16_rne(f1.x), bf16_rne(f1.y), bf16_rne(f1.z), bf16_rne(f1.w) };
                xv = *(const uint4*)us;
            }
        }
        *(uint4*)&sX[xr * 40 + xo] = xv;

        // --- stage W[128][32] (from n-major Wt: contiguous in k) ---
        const unsigned short* wp = Wt + (size_t)wn * 256 + k0 + wo;
        uint4 wv0 = *(const uint4*)(wp);
        uint4 wv1 = *(const uint4*)(wp + 8);
        *(uint4*)&sW[wn * 40 + wo] = wv0;
        *(uint4*)&sW[wn * 40 + wo + 8] = wv1;
        __syncthreads();

        short8 a = *(const short8*)&sX[(wave * 16 + ln16) * 40 + quad * 8];
#pragma unroll
        for (int ct = 0; ct < 8; ct++) {
            short8 b = *(const short8*)&sW[(ct * 16 + ln16) * 40 + quad * 8];
            acc[ct] = __builtin_amdgcn_mfma_f32_16x16x32_bf16(a, b, acc[ct], 0, 0, 0);
        }
        __syncthreads();
    }

    // --- epilogue ---
    float bb[8];
#pragma unroll
    for (int ct = 0; ct < 8; ct++) bb[ct] = bias[ct * 16 + ln16];

    float v[8][4];
#pragma unroll
    for (int ct = 0; ct < 8; ct++)
#pragma unroll
        for (int r = 0; r < 4; r++) v[ct][r] = acc[ct][r] + bb[ct];

    if (do_ln) {
        float gg[8], be[8];
#pragma unroll
        for (int ct = 0; ct < 8; ct++) {
            gg[ct] = ln_g[ct * 16 + ln16];
            be[ct] = ln_b[ct * 16 + ln16];
        }
        float s[4] = {0.f, 0.f, 0.f, 0.f}, s2[4] = {0.f, 0.f, 0.f, 0.f};
#pragma unroll
        for (int ct = 0; ct < 8; ct++)
#pragma unroll
            for (int r = 0; r < 4; r++) { s[r] += v[ct][r]; s2[r] += v[ct][r] * v[ct][r]; }
#pragma unroll
        for (int off = 1; off < 16; off <<= 1) {
#pragma unroll
            for (int r = 0; r < 4; r++) {
                s[r]  += __shfl_xor(s[r],  off);
                s2[r] += __shfl_xor(s2[r], off);
            }
        }
        float mean[4], rstd[4];
#pragma unroll
        for (int r = 0; r < 4; r++) {
            mean[r] = s[r] * (1.f / 128.f);
            float var = s2[r] * (1.f / 128.f) - mean[r] * mean[r];
            rstd[r] = rsqrtf(var + 1e-5f);
        }
#pragma unroll
        for (int r = 0; r < 4; r++) {
            int row_g = row0 + wave * 16 + quad * 4 + r;
            if (row_g < N) {
#pragma unroll
                for (int ct = 0; ct < 8; ct++) {
                    float t = (v[ct][r] - mean[r]) * rstd[r] * gg[ct] + be[ct];
                    t = t > 0.f ? t : 0.f;
                    Out16[(size_t)row_g * D + ct * 16 + ln16] = bf16_rne(t);
                }
            }
        }
    } else {
#pragma unroll
        for (int r = 0; r < 4; r++) {
            int row_g = row0 + wave * 16 + quad * 4 + r;
            if (row_g < N) {
#pragma unroll
                for (int ct = 0; ct < 8; ct++)
                    Out32[(size_t)row_g * D + ct * 16 + ln16] = v[ct][r];
            }
        }
    }
}

// ---------------------------------------------------------------------------
extern "C" void kernel_launch(void* const* d_in, const int* in_sizes, int n_in,
                              void* d_out, int out_size, void* d_ws, size_t ws_size,
                              hipStream_t stream)
{
    const float* feat = (const float*)d_in[0];
    const float* Ws0  = (const float*)d_in[1];
    const float* Wn0  = (const float*)d_in[2];
    const float* b0   = (const float*)d_in[3];
    const float* Ws1  = (const float*)d_in[4];
    const float* Wn1  = (const float*)d_in[5];
    const float* b1   = (const float*)d_in[6];
    const float* lng  = (const float*)d_in[7];
    const float* lnb  = (const float*)d_in[8];
    const int* esrc   = (const int*)d_in[9];
    const int* edst   = (const int*)d_in[10];
    const int* indeg  = (const int*)d_in[11];

    const int N = NN;
    const int E = in_sizes[9];

    float* out = (float*)d_out;
    float* msg = out;   // fp32 msg aliases d_out (per-block row ownership -> safe)

    // workspace layout (16B-aligned):
    //   feat16 | col | row_ptr | wt0 | wt1 | bsums | boffs | D-region
    //   D-region overlay: [counts + rank] (CSR build)  then  [h1_16] (compute)
    char* ws = (char*)d_ws;
    size_t o = 0;
    auto alloc = [&](size_t bytes) { char* p = ws + o; o += (bytes + 15) & ~(size_t)15; return p; };
    unsigned short* feat16 = (unsigned short*)alloc((size_t)N * D * 2);
    int* col     = (int*)alloc((size_t)E * 4);
    int* row_ptr = (int*)alloc((size_t)(N + 1) * 4);
    unsigned short* wt0 = (unsigned short*)alloc(128 * 256 * 2);
    unsigned short* wt1 = (unsigned short*)alloc(128 * 256 * 2);
    int* bsums = (int*)alloc(1024);
    int* boffs = (int*)alloc(1024);
    char* regD = alloc((size_t)N * D * 2 > ((size_t)N * 4 + (size_t)E * 4 + 32)
                       ? (size_t)N * D * 2 : ((size_t)N * 4 + (size_t)E * 4 + 32));
    int* counts = (int*)regD;
    int* rank   = (int*)(regD + (((size_t)N * 4 + 15) & ~(size_t)15));
    unsigned short* h116 = (unsigned short*)regD;
    (void)ws_size;

    const int edge_blocks = (E + 255) / 256;
    const int gemm_blocks = (N + 63) / 64;
    const int nb = (N + 1023) / 1024;

    // --- conversions (independent of CSR) ---
    cvt_bf16_kernel<<<(N * D / 4 + 255) / 256, 256, 0, stream>>>(feat, feat16, N * D / 4);
    build_wt_kernel<<<256, 256, 0, stream>>>(Ws0, Wn0, Ws1, Wn1, wt0, wt1);

    // --- CSR build ---
    hipMemsetAsync(counts, 0, (size_t)N * 4, stream);
    hist_rank_kernel<<<edge_blocks, 256, 0, stream>>>(edst, counts, rank, E);
    scan1_kernel<<<nb, 256, 0, stream>>>(counts, row_ptr, bsums, N);
    scan2_kernel<<<1, 256, 0, stream>>>(bsums, boffs, nb);
    scan3_kernel<<<(N + 256) / 256, 256, 0, stream>>>(row_ptr, boffs, N, E);
    fill_stream_kernel<<<edge_blocks, 256, 0, stream>>>(esrc, edst, row_ptr, rank, col, E);

    // --- Layer 0 ---
    gather_bf16_kernel<<<(N + 3) / 4, 256, 0, stream>>>(feat16, row_ptr, col, indeg, msg, N);
    mfma_layer_kernel<<<gemm_blocks, 256, 0, stream>>>(
        feat16, msg, wt0, b0, lng, lnb, h116, nullptr, N, 1);

    // --- Layer 1 ---
    gather_bf16_kernel<<<(N + 3) / 4, 256, 0, stream>>>(h116, row_ptr, col, indeg, msg, N);
    mfma_layer_kernel<<<gemm_blocks, 256, 0, stream>>>(
        h116, msg, wt1, b1, nullptr, nullptr, nullptr, out, N, 0);
}